// Round 1
// baseline (1246.714 us; speedup 1.0000x reference)
//
#include <hip/hip_runtime.h>
#include <math.h>

#define FRAME_LEN 882
#define FRAME_HOP 441
#define NFFT 2048
#define NBINS 1025           // NFFT/2 + 1
#define NFRAMES 999
#define NBATCH 16
#define NMEL 60
#define WAVE_LEN 441000
#define PRE_EMPH 0.97f
#define EPS 1e-10f

// Kernel A: one block per (frame t, batch b).
// Pre-emphasis + Hamming window on the fly, 2048-pt complex radix-2 FFT in LDS,
// power spectrum, then 60 mel dot-products (one wave per filter, strided lanes),
// log -> logmel[b, t, m].
__global__ __launch_bounds__(256) void fft_mel_kernel(
    const float* __restrict__ wav, const float* __restrict__ filt,
    float* __restrict__ logmel)
{
    __shared__ float re[NFFT];
    __shared__ float im[NFFT];
    const int t   = blockIdx.x;
    const int b   = blockIdx.y;
    const int tid = threadIdx.x;
    const float* w = wav + (size_t)b * WAVE_LEN;
    const int start = t * FRAME_HOP;

    // ---- load (bit-reversed) with pre-emphasis + hamming window ----
    for (int i = tid; i < NFFT; i += 256) {
        float v = 0.f;
        if (i < FRAME_LEN) {
            int s = start + i;
            float x  = w[s];
            float e;
            if (s > 0) {
                float xp = w[s - 1];
                e = x - PRE_EMPH * xp;
            } else {
                e = x;  // emph[0] = waveform[0]
            }
            // np.hamming(882): 0.54 - 0.46*cos(2*pi*i/881)
            float win = 0.54f - 0.46f * cosf(6.283185307179586f * (float)i / 881.0f);
            v = e * win;
        }
        unsigned r = __brev((unsigned)i) >> 21;  // 11-bit reversal
        re[r] = v;
        im[r] = 0.f;
    }
    __syncthreads();

    // ---- iterative radix-2 DIT, 11 stages ----
    for (int s = 0; s < 11; ++s) {
        const int half = 1 << s;
        const float base = -3.14159265358979323846f / (float)half;  // -2pi/len
        for (int j = tid; j < NFFT / 2; j += 256) {
            int k  = j & (half - 1);
            int i0 = ((j >> s) << (s + 1)) | k;
            int i1 = i0 + half;
            float ang = base * (float)k;
            float wr, wi;
            sincosf(ang, &wi, &wr);   // wi = sin(ang), wr = cos(ang)
            float ur = re[i0], ui = im[i0];
            float xr = re[i1], xi = im[i1];
            float vr = xr * wr - xi * wi;
            float vi = xr * wi + xi * wr;
            re[i0] = ur + vr; im[i0] = ui + vi;
            re[i1] = ur - vr; im[i1] = ui - vi;
        }
        __syncthreads();
    }

    // ---- power spectrum into im[0..1024] (each thread touches only its own f) ----
    for (int f = tid; f < NBINS; f += 256) {
        float a = re[f], c = im[f];
        im[f] = a * a + c * c;
    }
    __syncthreads();

    // ---- mel projection + log: one wave per filter, lanes stride over bins ----
    const int wave = tid >> 6;
    const int lane = tid & 63;
    float* out = logmel + ((size_t)(b * NFRAMES + t)) * NMEL;
    for (int m = wave; m < NMEL; m += 4) {
        const float* fr = filt + (size_t)m * NBINS;
        float p = 0.f;
        for (int f = lane; f < NBINS; f += 64)
            p += fr[f] * im[f];
        // full 64-lane butterfly reduction
        for (int o = 32; o > 0; o >>= 1)
            p += __shfl_xor(p, o, 64);
        if (lane == 0)
            out[m] = logf(p + EPS);
    }
}

// Kernel B: one block per batch, thread j in [0,90) owns one feature.
// Two-pass mean / std (ddof=1) over the 999 frames.
__global__ __launch_bounds__(128) void stats_kernel(
    const float* __restrict__ logmel, float* __restrict__ out)
{
    const int b = blockIdx.x;
    const int j = threadIdx.x;
    if (j >= 90) return;
    const float* lm = logmel + (size_t)b * NFRAMES * NMEL;
    const float inv_sq2 = 0.7071067811865475f;

    auto feat = [&](int t) -> float {
        if (j < 30) {
            int m = j;
            return (lm[t * NMEL + 2 * m] + lm[t * NMEL + 2 * m + 1]) * inv_sq2;
        } else if (j < 60) {
            int m  = j - 30;
            int tp = (t + 1 > NFRAMES - 1) ? (NFRAMES - 1) : (t + 1);
            int tm = (t - 1 < 0) ? 0 : (t - 1);
            float ca_p = (lm[tp * NMEL + 2 * m] + lm[tp * NMEL + 2 * m + 1]) * inv_sq2;
            float ca_m = (lm[tm * NMEL + 2 * m] + lm[tm * NMEL + 2 * m + 1]) * inv_sq2;
            return ca_p - ca_m;
        } else {
            int m = j - 60;
            return (lm[t * NMEL + 2 * m] - lm[t * NMEL + 2 * m + 1]) * inv_sq2;
        }
    };

    float sum = 0.f;
    for (int t = 0; t < NFRAMES; ++t) sum += feat(t);
    float mean = sum / (float)NFRAMES;

    float s2 = 0.f;
    for (int t = 0; t < NFRAMES; ++t) {
        float d = feat(t) - mean;
        s2 += d * d;
    }
    float stdv = sqrtf(s2 / (float)(NFRAMES - 1));

    out[b * 180 + j]      = mean;
    out[b * 180 + 90 + j] = stdv;
}

extern "C" void kernel_launch(void* const* d_in, const int* in_sizes, int n_in,
                              void* d_out, int out_size, void* d_ws, size_t ws_size,
                              hipStream_t stream) {
    const float* wav  = (const float*)d_in[0];   // (16, 441000) f32
    const float* filt = (const float*)d_in[1];   // (60, 1025) f32
    float* out    = (float*)d_out;               // (16, 180) f32
    float* logmel = (float*)d_ws;                // 16*999*60 f32 = 3.84 MB

    fft_mel_kernel<<<dim3(NFRAMES, NBATCH), 256, 0, stream>>>(wav, filt, logmel);
    stats_kernel<<<NBATCH, 128, 0, stream>>>(logmel, out);
}

// Round 2
// 416.943 us; speedup vs baseline: 2.9901x; 2.9901x over previous
//
#include <hip/hip_runtime.h>
#include <math.h>

#define FRAME_LEN 882
#define FRAME_HOP 441
#define NFFT 2048
#define NBINS 1025           // NFFT/2 + 1
#define NFRAMES 999
#define NBATCH 16
#define NMEL 60
#define WAVE_LEN 441000
#define PRE_EMPH 0.97f
#define EPS 1e-10f

// Kernel A: one block per (frame-pair, batch). Two real frames are packed as
// real+imag of ONE 2048-pt complex FFT, then separated into the two rffts.
// Pre-emphasis + Hamming on the fly; fast HW trig (__sincosf) for twiddles;
// power spectra in LDS; 60 mel dot-products (wave per filter, both frames at
// once, amortizing the filter read); log -> logmel[b, t, m].
__global__ __launch_bounds__(256) void fft_mel_kernel(
    const float* __restrict__ wav, const float* __restrict__ filt,
    float* __restrict__ logmel)
{
    __shared__ float re[NFFT];
    __shared__ float im[NFFT];
    __shared__ float p1[NBINS];
    __shared__ float p2[NBINS];

    const int t0  = 2 * blockIdx.x;
    const int t1  = t0 + 1;                 // may be == NFRAMES (invalid)
    const bool has_t1 = (t1 < NFRAMES);
    const int b   = blockIdx.y;
    const int tid = threadIdx.x;
    const float* w = wav + (size_t)b * WAVE_LEN;
    const int s0 = t0 * FRAME_HOP;
    const int s1 = t1 * FRAME_HOP;

    // ---- load (bit-reversed): re = windowed frame t0, im = windowed frame t1
    for (int i = tid; i < NFFT; i += 256) {
        float v1 = 0.f, v2 = 0.f;
        if (i < FRAME_LEN) {
            // np.hamming(882): 0.54 - 0.46*cos(2*pi*i/881)
            float win = 0.54f - 0.46f * __cosf(6.283185307179586f * (float)i / 881.0f);
            {
                int s = s0 + i;
                float x = w[s];
                float e = (s > 0) ? (x - PRE_EMPH * w[s - 1]) : x;
                v1 = e * win;
            }
            if (has_t1) {
                int s = s1 + i;
                float x = w[s];
                float e = x - PRE_EMPH * w[s - 1];   // s1 >= 441 > 0 always
                v2 = e * win;
            }
        }
        unsigned r = __brev((unsigned)i) >> 21;  // 11-bit reversal
        re[r] = v1;
        im[r] = v2;
    }
    __syncthreads();

    // ---- iterative radix-2 DIT, 11 stages, 4 butterflies per thread ----
    for (int s = 0; s < 11; ++s) {
        const int half = 1 << s;
        const float base = -3.14159265358979323846f / (float)half;  // -2pi/len
#pragma unroll
        for (int r4 = 0; r4 < 4; ++r4) {
            int j  = tid + (r4 << 8);
            int k  = j & (half - 1);
            int i0 = ((j >> s) << (s + 1)) | k;
            int i1 = i0 + half;
            float wr, wi;
            __sincosf(base * (float)k, &wi, &wr);   // wi=sin, wr=cos
            float ur = re[i0], ui = im[i0];
            float xr = re[i1], xi = im[i1];
            float vr = xr * wr - xi * wi;
            float vi = xr * wi + xi * wr;
            re[i0] = ur + vr; im[i0] = ui + vi;
            re[i1] = ur - vr; im[i1] = ui - vi;
        }
        __syncthreads();
    }

    // ---- separate the two rffts and form power spectra ----
    // F1[k] = (Z[k] + conj(Z[N-k]))/2 ; F2[k] = (Z[k] - conj(Z[N-k]))/(2i)
    for (int k = tid; k < NBINS; k += 256) {
        int nk = (NFFT - k) & (NFFT - 1);
        float zr = re[k],  zi = im[k];
        float yr = re[nk], yi = im[nk];
        float f1r = zr + yr, f1i = zi - yi;
        float f2r = zi + yi, f2i = yr - zr;
        p1[k] = 0.25f * (f1r * f1r + f1i * f1i);
        p2[k] = 0.25f * (f2r * f2r + f2i * f2i);
    }
    __syncthreads();

    // ---- mel projection + log: one wave per filter, both frames at once ----
    const int wave = tid >> 6;
    const int lane = tid & 63;
    float* out0 = logmel + ((size_t)(b * NFRAMES + t0)) * NMEL;
    float* out1 = logmel + ((size_t)(b * NFRAMES + t1)) * NMEL;
    for (int m = wave; m < NMEL; m += 4) {
        const float* fr = filt + (size_t)m * NBINS;
        float d1 = 0.f, d2 = 0.f;
        for (int f = lane; f < NBINS; f += 64) {
            float c = fr[f];
            d1 += c * p1[f];
            d2 += c * p2[f];
        }
        for (int o = 32; o > 0; o >>= 1) {
            d1 += __shfl_xor(d1, o, 64);
            d2 += __shfl_xor(d2, o, 64);
        }
        if (lane == 0) {
            out0[m] = __logf(d1 + EPS);
            if (has_t1) out1[m] = __logf(d2 + EPS);
        }
    }
}

// Kernel B: one block per (feature j, batch b), 256 threads over frames.
// Each thread keeps its <=4 frame-features in registers; two-pass mean/std.
__global__ __launch_bounds__(256) void stats_kernel(
    const float* __restrict__ logmel, float* __restrict__ out)
{
    __shared__ float red[4];
    const int j   = blockIdx.x;   // 0..89
    const int b   = blockIdx.y;   // 0..15
    const int tid = threadIdx.x;
    const float* lm = logmel + (size_t)b * NFRAMES * NMEL;
    const float inv_sq2 = 0.7071067811865475f;

    // compute this thread's frame-features into registers
    float fv[4];
    int   nf = 0;
#pragma unroll
    for (int r = 0; r < 4; ++r) {
        int t = tid + (r << 8);
        if (t < NFRAMES) {
            float v;
            if (j < 30) {
                int m = j;
                v = (lm[t * NMEL + 2 * m] + lm[t * NMEL + 2 * m + 1]) * inv_sq2;
            } else if (j < 60) {
                int m  = j - 30;
                int tp = (t + 1 > NFRAMES - 1) ? (NFRAMES - 1) : (t + 1);
                int tm = (t - 1 < 0) ? 0 : (t - 1);
                float ca_p = (lm[tp * NMEL + 2 * m] + lm[tp * NMEL + 2 * m + 1]) * inv_sq2;
                float ca_m = (lm[tm * NMEL + 2 * m] + lm[tm * NMEL + 2 * m + 1]) * inv_sq2;
                v = ca_p - ca_m;
            } else {
                int m = j - 60;
                v = (lm[t * NMEL + 2 * m] - lm[t * NMEL + 2 * m + 1]) * inv_sq2;
            }
            fv[nf++] = v;
        }
    }

    // ---- pass 1: mean ----
    float s = 0.f;
    for (int r = 0; r < nf; ++r) s += fv[r];
    for (int o = 32; o > 0; o >>= 1) s += __shfl_xor(s, o, 64);
    if ((tid & 63) == 0) red[tid >> 6] = s;
    __syncthreads();
    float mean = (red[0] + red[1] + red[2] + red[3]) / (float)NFRAMES;
    __syncthreads();

    // ---- pass 2: variance (ddof=1) ----
    float s2 = 0.f;
    for (int r = 0; r < nf; ++r) {
        float d = fv[r] - mean;
        s2 += d * d;
    }
    for (int o = 32; o > 0; o >>= 1) s2 += __shfl_xor(s2, o, 64);
    if ((tid & 63) == 0) red[tid >> 6] = s2;
    __syncthreads();
    float var = (red[0] + red[1] + red[2] + red[3]) / (float)(NFRAMES - 1);

    if (tid == 0) {
        out[b * 180 + j]      = mean;
        out[b * 180 + 90 + j] = sqrtf(var);
    }
}

extern "C" void kernel_launch(void* const* d_in, const int* in_sizes, int n_in,
                              void* d_out, int out_size, void* d_ws, size_t ws_size,
                              hipStream_t stream) {
    const float* wav  = (const float*)d_in[0];   // (16, 441000) f32
    const float* filt = (const float*)d_in[1];   // (60, 1025) f32
    float* out    = (float*)d_out;               // (16, 180) f32
    float* logmel = (float*)d_ws;                // 16*999*60 f32 = 3.84 MB

    fft_mel_kernel<<<dim3((NFRAMES + 1) / 2, NBATCH), 256, 0, stream>>>(wav, filt, logmel);
    stats_kernel<<<dim3(90, NBATCH), 256, 0, stream>>>(logmel, out);
}

// Round 3
// 134.961 us; speedup vs baseline: 9.2376x; 3.0894x over previous
//
#include <hip/hip_runtime.h>
#include <hip/hip_bf16.h>
#include <math.h>

#define FRAME_LEN 882
#define FRAME_HOP 441
#define NFFT 2048
#define NFRAMES 999
#define NBATCH 16
#define NMEL 60
#define WAVE_LEN 441000
#define PRE_EMPH 0.97f
#define EPS 1e-10f
#define NROWS (NBATCH * NFRAMES)     // 15984
#define KPAD 1056                    // 33*32; >=1025, multiple of 32 and 8
#define PI_F 3.14159265358979323846f

// LDS float2 index padding: +1 float2 per 16 -> breaks power-of-2 stride conflicts
#define PADI(i) ((i) + ((i) >> 4))

__device__ __forceinline__ float2 cadd(float2 a, float2 b){ return make_float2(a.x+b.x, a.y+b.y); }
__device__ __forceinline__ float2 csub(float2 a, float2 b){ return make_float2(a.x-b.x, a.y-b.y); }
__device__ __forceinline__ float2 cmul(float2 a, float2 b){ return make_float2(a.x*b.x - a.y*b.y, a.x*b.y + a.y*b.x); }
__device__ __forceinline__ float2 tw(float ang){ float s, c; __sincosf(ang, &s, &c); return make_float2(c, s); }

// Three consecutive DIF (Gentleman-Sande) radix-2 stages entirely in registers.
// Thread owns elements e_k = q*(8S) + k*S + r (k=0..7). Stage half-sizes 4S,2S,S.
// Twiddle index of element i0 at half h is (i0 mod h); for this ownership it
// reduces to the formulas below (r = t mod S).
#define DIF_GROUP(S)                                                        \
  {                                                                         \
    const float fr = (float)r;                                              \
    _Pragma("unroll")                                                       \
    for (int k = 0; k < 4; ++k) {                                           \
      float2 wk = tw(-PI_F * ((float)(k*(S)) + fr) / (float)(4*(S)));       \
      float2 u = x[k], v = x[k+4];                                          \
      x[k] = cadd(u, v); x[k+4] = cmul(csub(u, v), wk);                     \
    }                                                                       \
    {                                                                       \
      float2 w0 = tw(-PI_F * fr / (float)(2*(S)));                          \
      float2 w1 = tw(-PI_F * ((float)(S) + fr) / (float)(2*(S)));           \
      float2 u, v;                                                          \
      u=x[0]; v=x[2]; x[0]=cadd(u,v); x[2]=cmul(csub(u,v), w0);             \
      u=x[1]; v=x[3]; x[1]=cadd(u,v); x[3]=cmul(csub(u,v), w1);             \
      u=x[4]; v=x[6]; x[4]=cadd(u,v); x[6]=cmul(csub(u,v), w0);             \
      u=x[5]; v=x[7]; x[5]=cadd(u,v); x[7]=cmul(csub(u,v), w1);             \
    }                                                                       \
    {                                                                       \
      float2 w0 = tw(-PI_F * fr / (float)(S));                              \
      float2 u, v;                                                          \
      u=x[0]; v=x[1]; x[0]=cadd(u,v); x[1]=cmul(csub(u,v), w0);             \
      u=x[2]; v=x[3]; x[2]=cadd(u,v); x[3]=cmul(csub(u,v), w0);             \
      u=x[4]; v=x[5]; x[4]=cadd(u,v); x[5]=cmul(csub(u,v), w0);             \
      u=x[6]; v=x[7]; x[6]=cadd(u,v); x[7]=cmul(csub(u,v), w0);             \
    }                                                                       \
  }

// Final two DIF stages (1,0) on 4 consecutive elements: twiddles are 1 and -i.
__device__ __forceinline__ void dif_radix4(float2* x) {
  float2 y0 = cadd(x[0], x[2]);
  float2 y2 = csub(x[0], x[2]);
  float2 y1 = cadd(x[1], x[3]);
  float2 t3 = csub(x[1], x[3]);
  float2 y3 = make_float2(t3.y, -t3.x);  // * (-i)
  x[0] = cadd(y0, y1); x[1] = csub(y0, y1);
  x[2] = cadd(y2, y3); x[3] = csub(y2, y3);
}

// Kernel 1: one block per (frame-pair, batch). Two real frames packed as
// real+imag of one 2048-pt complex DIF FFT (natural in, bit-reversed out).
// Radix-8 register blocking: 4 LDS exchange rounds total. Separates the two
// rffts via Z[k], conj(Z[N-k]) (read at bit-reversed LDS positions) and writes
// bf16 power spectra, K-padded to KPAD with zeros.
__global__ __launch_bounds__(256) void fft_pow_kernel(
    const float* __restrict__ wav, __hip_bfloat16* __restrict__ powr)
{
  __shared__ float2 lds[NFFT + (NFFT >> 4)];   // 2176 float2 = 17.4 KB
  const int t  = threadIdx.x;
  const int t0 = 2 * blockIdx.x, t1 = t0 + 1;
  const bool has1 = (t1 < NFRAMES);
  const int b = blockIdx.y;
  const float* w = wav + (size_t)b * WAVE_LEN;
  const int s0 = t0 * FRAME_HOP, s1 = t1 * FRAME_HOP;

  float2 x[8];
  // ---- load + pre-emphasis + Hamming: element i = k*256 + t (natural order)
#pragma unroll
  for (int k = 0; k < 8; ++k) {
    int i = k * 256 + t;
    float v1 = 0.f, v2 = 0.f;
    if (i < FRAME_LEN) {
      float win = 0.54f - 0.46f * __cosf(6.283185307179586f * (float)i / 881.0f);
      int s = s0 + i;
      float e1 = (s > 0) ? (w[s] - PRE_EMPH * w[s - 1]) : w[s];
      v1 = e1 * win;
      if (has1) {
        int ss = s1 + i;                    // ss >= 441 > 0 always
        v2 = (w[ss] - PRE_EMPH * w[ss - 1]) * win;
      }
    }
    x[k] = make_float2(v1, v2);
  }

  // ---- G0: stages 10,9,8 (S=256, ownership k*256 + t) — straight from load
  { const int r = t; DIF_GROUP(256) }
#pragma unroll
  for (int k = 0; k < 8; ++k) lds[PADI(k * 256 + t)] = x[k];
  __syncthreads();

  // ---- G1: stages 7,6,5 (S=32)
  {
    const int q = t >> 5, r = t & 31;
#pragma unroll
    for (int k = 0; k < 8; ++k) x[k] = lds[PADI(q * 256 + k * 32 + r)];
    DIF_GROUP(32)
#pragma unroll
    for (int k = 0; k < 8; ++k) lds[PADI(q * 256 + k * 32 + r)] = x[k];
  }
  __syncthreads();

  // ---- G2: stages 4,3,2 (S=4)
  {
    const int q = t >> 2, r = t & 3;
#pragma unroll
    for (int k = 0; k < 8; ++k) x[k] = lds[PADI(q * 32 + k * 4 + r)];
    DIF_GROUP(4)
#pragma unroll
    for (int k = 0; k < 8; ++k) lds[PADI(q * 32 + k * 4 + r)] = x[k];
  }
  __syncthreads();

  // ---- G3: stages 1,0 — two radix-4 groups of 4 consecutive elements
  {
    float2 xa[4], xb[4];
#pragma unroll
    for (int j = 0; j < 4; ++j) {
      xa[j] = lds[PADI(4 * t + j)];
      xb[j] = lds[PADI(4 * (t + 256) + j)];
    }
    dif_radix4(xa);
    dif_radix4(xb);
#pragma unroll
    for (int j = 0; j < 4; ++j) {
      lds[PADI(4 * t + j)] = xa[j];
      lds[PADI(4 * (t + 256) + j)] = xb[j];
    }
  }
  __syncthreads();

  // ---- power separation + bf16 store (spectrum lives bit-reversed in LDS)
  const size_t row0 = (size_t)b * NFRAMES + t0;
  __hip_bfloat16* p0 = powr + row0 * KPAD;
  __hip_bfloat16* p1 = powr + (row0 + 1) * KPAD;
#pragma unroll
  for (int c = 0; c < 5; ++c) {
    int f = t + 256 * c;
    bool valid = (c < 4) || (t == 0);
    if (c == 4) f = 1024;
    if (valid) {
      int j1 = (int)(__brev((unsigned)f) >> 21);
      int j2 = (int)(__brev((unsigned)((NFFT - f) & (NFFT - 1))) >> 21);
      float2 z = lds[PADI(j1)];
      float2 y = lds[PADI(j2)];
      float f1r = z.x + y.x, f1i = z.y - y.y;
      float f2r = z.y + y.y, f2i = y.x - z.x;
      float pw1 = 0.25f * (f1r * f1r + f1i * f1i);
      float pw2 = 0.25f * (f2r * f2r + f2i * f2i);
      p0[f] = __float2bfloat16(pw1);
      if (has1) p1[f] = __float2bfloat16(pw2);
    }
  }
  // zero the K pads (1025..KPAD-1)
  if (t < KPAD - 1025) {
    p0[1025 + t] = __float2bfloat16(0.f);
    if (has1) p1[1025 + t] = __float2bfloat16(0.f);
  }
}

// Kernel 0: filt (60x1025 f32) -> bf16, padded to 64 rows x KPAD cols, pads zero.
__global__ __launch_bounds__(256) void filtconv_kernel(
    const float* __restrict__ filt, __hip_bfloat16* __restrict__ filtb)
{
  const int m = blockIdx.x;  // 0..63
  for (int k = threadIdx.x; k < KPAD; k += 256) {
    float v = (m < NMEL && k < 1025) ? filt[m * 1025 + k] : 0.f;
    filtb[(size_t)m * KPAD + k] = __float2bfloat16(v);
  }
}

// Kernel 2: mel GEMM via MFMA. D[row][mel] = sum_k P[row][k] * filt[mel][k].
// Block = 256 thr = 4 waves; wave w -> mel tile [16w,16w+16); block -> 32 rows
// (2 row-tiles of 16). Fragments gathered directly from global (A chunk is
// 4 KB/block -> L1-resident across the 4 waves). K = KPAD in 33 chunks of 32.
typedef __attribute__((ext_vector_type(8))) short short8x;
typedef __attribute__((ext_vector_type(4))) float float4x;

__global__ __launch_bounds__(256) void melgemm_kernel(
    const __hip_bfloat16* __restrict__ powr,
    const __hip_bfloat16* __restrict__ filtb,
    float* __restrict__ logmel)
{
  const int wave = threadIdx.x >> 6, lane = threadIdx.x & 63;
  const int row0 = blockIdx.x * 32;
  const int melbase = wave * 16;
  const int lrow = lane & 15, kgrp = lane >> 4;   // A-frag: A[m=lane&15][k=(lane>>4)*8+j]

  int r0 = row0 + lrow;        if (r0 > NROWS - 1) r0 = NROWS - 1;
  int r1 = row0 + 16 + lrow;   if (r1 > NROWS - 1) r1 = NROWS - 1;
  const __hip_bfloat16* a0p = powr + (size_t)r0 * KPAD + kgrp * 8;
  const __hip_bfloat16* a1p = powr + (size_t)r1 * KPAD + kgrp * 8;
  const __hip_bfloat16* bp  = filtb + (size_t)(melbase + lrow) * KPAD + kgrp * 8;

  float4x acc0 = {0.f, 0.f, 0.f, 0.f};
  float4x acc1 = {0.f, 0.f, 0.f, 0.f};
  for (int kk = 0; kk < KPAD; kk += 32) {
    short8x a0 = *(const short8x*)a0p;
    short8x a1 = *(const short8x*)a1p;
    short8x bf = *(const short8x*)bp;
    acc0 = __builtin_amdgcn_mfma_f32_16x16x32_bf16(a0, bf, acc0, 0, 0, 0);
    acc1 = __builtin_amdgcn_mfma_f32_16x16x32_bf16(a1, bf, acc1, 0, 0, 0);
    a0p += 32; a1p += 32; bp += 32;
  }

  // C/D layout (m89-verified): col = lane&15, row = (lane>>4)*4 + reg
  const int mel = melbase + (lane & 15);
  const int rsub = (lane >> 4) * 4;
  if (mel < NMEL) {
#pragma unroll
    for (int reg = 0; reg < 4; ++reg) {
      int rowA = row0 + rsub + reg;
      if (rowA < NROWS) logmel[(size_t)rowA * NMEL + mel] = __logf(acc0[reg] + EPS);
      int rowB = rowA + 16;
      if (rowB < NROWS) logmel[(size_t)rowB * NMEL + mel] = __logf(acc1[reg] + EPS);
    }
  }
}

// Kernel 3: stats — one block per (feature j, batch b); two-pass mean/std.
__global__ __launch_bounds__(256) void stats_kernel(
    const float* __restrict__ logmel, float* __restrict__ out)
{
  __shared__ float red[4];
  const int j   = blockIdx.x;   // 0..89
  const int b   = blockIdx.y;   // 0..15
  const int tid = threadIdx.x;
  const float* lm = logmel + (size_t)b * NFRAMES * NMEL;
  const float inv_sq2 = 0.7071067811865475f;

  float fv[4];
  int   nf = 0;
#pragma unroll
  for (int r = 0; r < 4; ++r) {
    int tt = tid + (r << 8);
    if (tt < NFRAMES) {
      float v;
      if (j < 30) {
        int m = j;
        v = (lm[tt * NMEL + 2 * m] + lm[tt * NMEL + 2 * m + 1]) * inv_sq2;
      } else if (j < 60) {
        int m  = j - 30;
        int tp = (tt + 1 > NFRAMES - 1) ? (NFRAMES - 1) : (tt + 1);
        int tm = (tt - 1 < 0) ? 0 : (tt - 1);
        float ca_p = (lm[tp * NMEL + 2 * m] + lm[tp * NMEL + 2 * m + 1]) * inv_sq2;
        float ca_m = (lm[tm * NMEL + 2 * m] + lm[tm * NMEL + 2 * m + 1]) * inv_sq2;
        v = ca_p - ca_m;
      } else {
        int m = j - 60;
        v = (lm[tt * NMEL + 2 * m] - lm[tt * NMEL + 2 * m + 1]) * inv_sq2;
      }
      fv[nf++] = v;
    }
  }

  float s = 0.f;
  for (int r = 0; r < nf; ++r) s += fv[r];
  for (int o = 32; o > 0; o >>= 1) s += __shfl_xor(s, o, 64);
  if ((tid & 63) == 0) red[tid >> 6] = s;
  __syncthreads();
  float mean = (red[0] + red[1] + red[2] + red[3]) / (float)NFRAMES;
  __syncthreads();

  float s2 = 0.f;
  for (int r = 0; r < nf; ++r) { float d = fv[r] - mean; s2 += d * d; }
  for (int o = 32; o > 0; o >>= 1) s2 += __shfl_xor(s2, o, 64);
  if ((tid & 63) == 0) red[tid >> 6] = s2;
  __syncthreads();
  float var = (red[0] + red[1] + red[2] + red[3]) / (float)(NFRAMES - 1);

  if (tid == 0) {
    out[b * 180 + j]      = mean;
    out[b * 180 + 90 + j] = sqrtf(var);
  }
}

extern "C" void kernel_launch(void* const* d_in, const int* in_sizes, int n_in,
                              void* d_out, int out_size, void* d_ws, size_t ws_size,
                              hipStream_t stream) {
  const float* wav  = (const float*)d_in[0];   // (16, 441000) f32
  const float* filt = (const float*)d_in[1];   // (60, 1025) f32
  float* out = (float*)d_out;                  // (16, 180) f32

  // ws layout (bytes): power bf16 [NROWS][KPAD], filt bf16 [64][KPAD], logmel f32 [NROWS][60]
  unsigned char* ws = (unsigned char*)d_ws;
  __hip_bfloat16* powr  = (__hip_bfloat16*)(ws);
  size_t off = (size_t)NROWS * KPAD * 2;                      // 33,758,208
  __hip_bfloat16* filtb = (__hip_bfloat16*)(ws + off);
  off += (size_t)64 * KPAD * 2;                               // +135,168
  float* logmel = (float*)(ws + off);                         // +3,836,160 => ~37.7 MB

  filtconv_kernel<<<64, 256, 0, stream>>>(filt, filtb);
  fft_pow_kernel<<<dim3((NFRAMES + 1) / 2, NBATCH), 256, 0, stream>>>(wav, powr);
  melgemm_kernel<<<(NROWS + 31) / 32, 256, 0, stream>>>(powr, filtb, logmel);
  stats_kernel<<<dim3(90, NBATCH), 256, 0, stream>>>(logmel, out);
}

// Round 4
// 134.586 us; speedup vs baseline: 9.2633x; 1.0028x over previous
//
#include <hip/hip_runtime.h>
#include <hip/hip_bf16.h>
#include <math.h>

#define FRAME_LEN 882
#define FRAME_HOP 441
#define NFFT 2048
#define NFRAMES 999
#define NBATCH 16
#define NMEL 60
#define WAVE_LEN 441000
#define PRE_EMPH 0.97f
#define EPS 1e-10f
#define NROWS (NBATCH * NFRAMES)     // 15984
#define KPAD 1056                    // 33*32; >=1025, multiple of 32 and 8
#define PI_F 3.14159265358979323846f

// LDS float2 index padding: +1 float2 per 16 -> breaks power-of-2 stride conflicts
#define PADI(i) ((i) + ((i) >> 4))

__device__ __forceinline__ float2 cadd(float2 a, float2 b){ return make_float2(a.x+b.x, a.y+b.y); }
__device__ __forceinline__ float2 csub(float2 a, float2 b){ return make_float2(a.x-b.x, a.y-b.y); }
__device__ __forceinline__ float2 cmul(float2 a, float2 b){ return make_float2(a.x*b.x - a.y*b.y, a.x*b.y + a.y*b.x); }
__device__ __forceinline__ float2 rotni(float2 z){ return make_float2(z.y, -z.x); }  // z * (-i)

// Four consecutive DIF radix-2 stages (halves 8S,4S,2S,S) in registers.
// Thread owns e_k = Q*16S + k*S + r (k=0..15). ALL twiddles derive from
// t1 = e^{-i*pi*r/(8S)}: stage twiddles are t1^{1,2,4,8} times the
// compile-time constants e^{-i*pi*k/8}, with w_{k+4} = -i*w_k free.
__device__ __forceinline__ void dif_group16(float2* x, float2 t1) {
  const float2 C81 = make_float2(0.9238795325f, -0.3826834324f);
  const float2 C82 = make_float2(0.7071067812f, -0.7071067812f);
  const float2 C83 = make_float2(0.3826834324f, -0.9238795325f);
  // stage half = 8S
  float2 w0 = t1, w1 = cmul(t1, C81), w2 = cmul(t1, C82), w3 = cmul(t1, C83);
  float2 ws1[8] = {w0, w1, w2, w3, rotni(w0), rotni(w1), rotni(w2), rotni(w3)};
#pragma unroll
  for (int k = 0; k < 8; ++k) {
    float2 u = x[k], v = x[k + 8];
    x[k] = cadd(u, v);
    x[k + 8] = cmul(csub(u, v), ws1[k]);
  }
  // stage half = 4S
  float2 t2 = cmul(t1, t1);
  float2 v1 = cmul(t2, C82);
  float2 ws2[4] = {t2, v1, rotni(t2), rotni(v1)};
#pragma unroll
  for (int h = 0; h < 2; ++h) {
#pragma unroll
    for (int k = 0; k < 4; ++k) {
      float2 u = x[h*8 + k], v = x[h*8 + k + 4];
      x[h*8 + k] = cadd(u, v);
      x[h*8 + k + 4] = cmul(csub(u, v), ws2[k]);
    }
  }
  // stage half = 2S
  float2 t4 = cmul(t2, t2);
  float2 t4r = rotni(t4);
#pragma unroll
  for (int h = 0; h < 4; ++h) {
    float2 a = x[h*4 + 0], b = x[h*4 + 2];
    x[h*4 + 0] = cadd(a, b); x[h*4 + 2] = cmul(csub(a, b), t4);
    a = x[h*4 + 1]; b = x[h*4 + 3];
    x[h*4 + 1] = cadd(a, b); x[h*4 + 3] = cmul(csub(a, b), t4r);
  }
  // stage half = S
  float2 t8 = cmul(t4, t4);
#pragma unroll
  for (int j = 0; j < 8; ++j) {
    float2 a = x[2*j], b = x[2*j + 1];
    x[2*j] = cadd(a, b); x[2*j + 1] = cmul(csub(a, b), t8);
  }
}

// Final 3 DIF stages (halves 4,2,1) on 8 consecutive elements: constant twiddles.
__device__ __forceinline__ void dif8(float2* y) {
  const float2 c1 = make_float2(0.7071067812f, -0.7071067812f);
  const float2 c3 = make_float2(-0.7071067812f, -0.7071067812f);
  float2 u, v;
  u=y[0]; v=y[4]; y[0]=cadd(u,v); y[4]=csub(u,v);
  u=y[1]; v=y[5]; y[1]=cadd(u,v); y[5]=cmul(csub(u,v), c1);
  u=y[2]; v=y[6]; y[2]=cadd(u,v); y[6]=rotni(csub(u,v));
  u=y[3]; v=y[7]; y[3]=cadd(u,v); y[7]=cmul(csub(u,v), c3);
  u=y[0]; v=y[2]; y[0]=cadd(u,v); y[2]=csub(u,v);
  u=y[1]; v=y[3]; y[1]=cadd(u,v); y[3]=rotni(csub(u,v));
  u=y[4]; v=y[6]; y[4]=cadd(u,v); y[6]=csub(u,v);
  u=y[5]; v=y[7]; y[5]=cadd(u,v); y[7]=rotni(csub(u,v));
  u=y[0]; v=y[1]; y[0]=cadd(u,v); y[1]=csub(u,v);
  u=y[2]; v=y[3]; y[2]=cadd(u,v); y[3]=csub(u,v);
  u=y[4]; v=y[5]; y[4]=cadd(u,v); y[5]=csub(u,v);
  u=y[6]; v=y[7]; y[6]=cadd(u,v); y[7]=csub(u,v);
}

// Kernel 1: 128 threads per block, one frame-pair per block. Two real frames
// packed as real+imag of one 2048-pt complex DIF FFT (natural in, bit-reversed
// out). Radix-16 register blocking: 16 float2/thread, stage plan 4+4+3, only
// 2 full LDS exchange rounds + 1 store round. One sincos per twiddle group,
// window via complex recurrence (4 sincos/thread total). Writes bf16 power
// spectra, K-padded to KPAD with zeros.
__global__ __launch_bounds__(128) void fft_pow_kernel(
    const float* __restrict__ wav, __hip_bfloat16* __restrict__ powr)
{
  __shared__ float2 lds[NFFT + (NFFT >> 4)];   // 2176 float2 = 17.4 KB
  const int t  = threadIdx.x;                  // 0..127
  const int t0 = 2 * blockIdx.x, t1f = t0 + 1;
  const bool has1 = (t1f < NFRAMES);
  const int b = blockIdx.y;
  const float* w = wav + (size_t)b * WAVE_LEN;
  const int s0 = t0 * FRAME_HOP, s1 = t1f * FRAME_HOP;

  float2 x[16];
  // ---- load + pre-emphasis + Hamming: element i = k*128 + t (natural order)
  // window cos(2*pi*i/881) = Re{ e^{i*B_t} * e^{i*k*Delta} }, one sincos + recurrence
  {
    float sB, cB, sD, cD;
    __sincosf(6.283185307179586f * (float)t / 881.0f, &sB, &cB);
    __sincosf(6.283185307179586f * 128.0f / 881.0f, &sD, &cD);
    float2 cur  = make_float2(cB, sB);
    float2 step = make_float2(cD, sD);
#pragma unroll
    for (int k = 0; k < 16; ++k) {
      int i = k * 128 + t;
      float v1 = 0.f, v2 = 0.f;
      if (i < FRAME_LEN) {
        float win = 0.54f - 0.46f * cur.x;
        int s = s0 + i;
        float e1 = (s > 0) ? (w[s] - PRE_EMPH * w[s - 1]) : w[s];
        v1 = e1 * win;
        if (has1) {
          int ss = s1 + i;                    // ss >= 441 > 0 always
          v2 = (w[ss] - PRE_EMPH * w[ss - 1]) * win;
        }
      }
      x[k] = make_float2(v1, v2);
      cur = cmul(cur, step);
    }
  }

  // ---- G0: stages halves 1024,512,256,128 (S=128, r=t) — straight from load
  {
    float sA, cA;
    __sincosf(-PI_F * (float)t / 1024.0f, &sA, &cA);
    dif_group16(x, make_float2(cA, sA));
  }
#pragma unroll
  for (int k = 0; k < 16; ++k) lds[PADI(k * 128 + t)] = x[k];
  __syncthreads();

  // ---- G1: halves 64,32,16,8 (S=8). Sub-FFT Q = t>>3 (contig 128-block), r = t&7
  {
    const int Q = t >> 3, r = t & 7;
    const int base = Q * 128 + r;
#pragma unroll
    for (int k = 0; k < 16; ++k) x[k] = lds[PADI(base + k * 8)];
    float sA, cA;
    __sincosf(-PI_F * (float)r / 64.0f, &sA, &cA);
    dif_group16(x, make_float2(cA, sA));
    __syncthreads();
#pragma unroll
    for (int k = 0; k < 16; ++k) lds[PADI(base + k * 8)] = x[k];
  }
  __syncthreads();

  // ---- G2: halves 4,2,1 — two 8-point const-twiddle FFTs on consecutive runs
  {
    float2 ya[8], yb[8];
#pragma unroll
    for (int j = 0; j < 8; ++j) {
      ya[j] = lds[PADI(16 * t + j)];
      yb[j] = lds[PADI(16 * t + 8 + j)];
    }
    dif8(ya);
    dif8(yb);
    __syncthreads();
#pragma unroll
    for (int j = 0; j < 8; ++j) {
      lds[PADI(16 * t + j)] = ya[j];
      lds[PADI(16 * t + 8 + j)] = yb[j];
    }
  }
  __syncthreads();

  // ---- power separation + bf16 store (spectrum is bit-reversed in LDS)
  const size_t row0 = (size_t)b * NFRAMES + t0;
  __hip_bfloat16* p0 = powr + row0 * KPAD;
  __hip_bfloat16* p1 = powr + (row0 + 1) * KPAD;
#pragma unroll
  for (int c = 0; c < 9; ++c) {
    int f = c * 128 + t;
    bool valid = (c < 8) || (t == 0);
    if (c == 8) f = 1024;
    if (valid) {
      int j1 = (int)(__brev((unsigned)f) >> 21);
      int j2 = (int)(__brev((unsigned)((NFFT - f) & (NFFT - 1))) >> 21);
      float2 z = lds[PADI(j1)];
      float2 y = lds[PADI(j2)];
      float f1r = z.x + y.x, f1i = z.y - y.y;
      float f2r = z.y + y.y, f2i = y.x - z.x;
      float pw1 = 0.25f * (f1r * f1r + f1i * f1i);
      float pw2 = 0.25f * (f2r * f2r + f2i * f2i);
      p0[f] = __float2bfloat16(pw1);
      if (has1) p1[f] = __float2bfloat16(pw2);
    }
  }
  // zero the K pads (1025..KPAD-1)
  if (t < KPAD - 1025) {
    p0[1025 + t] = __float2bfloat16(0.f);
    if (has1) p1[1025 + t] = __float2bfloat16(0.f);
  }
}

// Kernel 0: filt (60x1025 f32) -> bf16, padded to 64 rows x KPAD cols, pads zero.
__global__ __launch_bounds__(256) void filtconv_kernel(
    const float* __restrict__ filt, __hip_bfloat16* __restrict__ filtb)
{
  const int m = blockIdx.x;  // 0..63
  for (int k = threadIdx.x; k < KPAD; k += 256) {
    float v = (m < NMEL && k < 1025) ? filt[m * 1025 + k] : 0.f;
    filtb[(size_t)m * KPAD + k] = __float2bfloat16(v);
  }
}

// Kernel 2: mel GEMM via MFMA. D[row][mel] = sum_k P[row][k] * filt[mel][k].
typedef __attribute__((ext_vector_type(8))) short short8x;
typedef __attribute__((ext_vector_type(4))) float float4x;

__global__ __launch_bounds__(256) void melgemm_kernel(
    const __hip_bfloat16* __restrict__ powr,
    const __hip_bfloat16* __restrict__ filtb,
    float* __restrict__ logmel)
{
  const int wave = threadIdx.x >> 6, lane = threadIdx.x & 63;
  const int row0 = blockIdx.x * 32;
  const int melbase = wave * 16;
  const int lrow = lane & 15, kgrp = lane >> 4;   // A-frag: A[m=lane&15][k=(lane>>4)*8+j]

  int r0 = row0 + lrow;        if (r0 > NROWS - 1) r0 = NROWS - 1;
  int r1 = row0 + 16 + lrow;   if (r1 > NROWS - 1) r1 = NROWS - 1;
  const __hip_bfloat16* a0p = powr + (size_t)r0 * KPAD + kgrp * 8;
  const __hip_bfloat16* a1p = powr + (size_t)r1 * KPAD + kgrp * 8;
  const __hip_bfloat16* bp  = filtb + (size_t)(melbase + lrow) * KPAD + kgrp * 8;

  float4x acc0 = {0.f, 0.f, 0.f, 0.f};
  float4x acc1 = {0.f, 0.f, 0.f, 0.f};
  for (int kk = 0; kk < KPAD; kk += 32) {
    short8x a0 = *(const short8x*)a0p;
    short8x a1 = *(const short8x*)a1p;
    short8x bf = *(const short8x*)bp;
    acc0 = __builtin_amdgcn_mfma_f32_16x16x32_bf16(a0, bf, acc0, 0, 0, 0);
    acc1 = __builtin_amdgcn_mfma_f32_16x16x32_bf16(a1, bf, acc1, 0, 0, 0);
    a0p += 32; a1p += 32; bp += 32;
  }

  // C/D layout (m89-verified): col = lane&15, row = (lane>>4)*4 + reg
  const int mel = melbase + (lane & 15);
  const int rsub = (lane >> 4) * 4;
  if (mel < NMEL) {
#pragma unroll
    for (int reg = 0; reg < 4; ++reg) {
      int rowA = row0 + rsub + reg;
      if (rowA < NROWS) logmel[(size_t)rowA * NMEL + mel] = __logf(acc0[reg] + EPS);
      int rowB = rowA + 16;
      if (rowB < NROWS) logmel[(size_t)rowB * NMEL + mel] = __logf(acc1[reg] + EPS);
    }
  }
}

// Kernel 3: stats — one block per (feature j, batch b); two-pass mean/std.
__global__ __launch_bounds__(256) void stats_kernel(
    const float* __restrict__ logmel, float* __restrict__ out)
{
  __shared__ float red[4];
  const int j   = blockIdx.x;   // 0..89
  const int b   = blockIdx.y;   // 0..15
  const int tid = threadIdx.x;
  const float* lm = logmel + (size_t)b * NFRAMES * NMEL;
  const float inv_sq2 = 0.7071067811865475f;

  float fv[4];
  int   nf = 0;
#pragma unroll
  for (int r = 0; r < 4; ++r) {
    int tt = tid + (r << 8);
    if (tt < NFRAMES) {
      float v;
      if (j < 30) {
        int m = j;
        v = (lm[tt * NMEL + 2 * m] + lm[tt * NMEL + 2 * m + 1]) * inv_sq2;
      } else if (j < 60) {
        int m  = j - 30;
        int tp = (tt + 1 > NFRAMES - 1) ? (NFRAMES - 1) : (tt + 1);
        int tm = (tt - 1 < 0) ? 0 : (tt - 1);
        float ca_p = (lm[tp * NMEL + 2 * m] + lm[tp * NMEL + 2 * m + 1]) * inv_sq2;
        float ca_m = (lm[tm * NMEL + 2 * m] + lm[tm * NMEL + 2 * m + 1]) * inv_sq2;
        v = ca_p - ca_m;
      } else {
        int m = j - 60;
        v = (lm[tt * NMEL + 2 * m] - lm[tt * NMEL + 2 * m + 1]) * inv_sq2;
      }
      fv[nf++] = v;
    }
  }

  float s = 0.f;
  for (int r = 0; r < nf; ++r) s += fv[r];
  for (int o = 32; o > 0; o >>= 1) s += __shfl_xor(s, o, 64);
  if ((tid & 63) == 0) red[tid >> 6] = s;
  __syncthreads();
  float mean = (red[0] + red[1] + red[2] + red[3]) / (float)NFRAMES;
  __syncthreads();

  float s2 = 0.f;
  for (int r = 0; r < nf; ++r) { float d = fv[r] - mean; s2 += d * d; }
  for (int o = 32; o > 0; o >>= 1) s2 += __shfl_xor(s2, o, 64);
  if ((tid & 63) == 0) red[tid >> 6] = s2;
  __syncthreads();
  float var = (red[0] + red[1] + red[2] + red[3]) / (float)(NFRAMES - 1);

  if (tid == 0) {
    out[b * 180 + j]      = mean;
    out[b * 180 + 90 + j] = sqrtf(var);
  }
}

extern "C" void kernel_launch(void* const* d_in, const int* in_sizes, int n_in,
                              void* d_out, int out_size, void* d_ws, size_t ws_size,
                              hipStream_t stream) {
  const float* wav  = (const float*)d_in[0];   // (16, 441000) f32
  const float* filt = (const float*)d_in[1];   // (60, 1025) f32
  float* out = (float*)d_out;                  // (16, 180) f32

  // ws layout (bytes): power bf16 [NROWS][KPAD], filt bf16 [64][KPAD], logmel f32 [NROWS][60]
  unsigned char* ws = (unsigned char*)d_ws;
  __hip_bfloat16* powr  = (__hip_bfloat16*)(ws);
  size_t off = (size_t)NROWS * KPAD * 2;                      // 33,758,208
  __hip_bfloat16* filtb = (__hip_bfloat16*)(ws + off);
  off += (size_t)64 * KPAD * 2;                               // +135,168
  float* logmel = (float*)(ws + off);                         // +3,836,160 => ~37.7 MB

  filtconv_kernel<<<64, 256, 0, stream>>>(filt, filtb);
  fft_pow_kernel<<<dim3((NFRAMES + 1) / 2, NBATCH), 128, 0, stream>>>(wav, powr);
  melgemm_kernel<<<(NROWS + 31) / 32, 256, 0, stream>>>(powr, filtb, logmel);
  stats_kernel<<<dim3(90, NBATCH), 256, 0, stream>>>(logmel, out);
}